// Round 3
// baseline (555.471 us; speedup 1.0000x reference)
//
#include <hip/hip_runtime.h>
#include <math.h>

#define NB 1024
#define NF 36
#define ED 256
#define NK 8
#define NN2 1296   // 36*36
#define QPK 162    // 1296/8

typedef _Float16 f16;
typedef f16 f16x8 __attribute__((ext_vector_type(8)));
typedef float f32x4 __attribute__((ext_vector_type(4)));

#define WXSTR 136     // f16 per Wx half-row (128 + 8 pad); 272B = 17*16 (b128-aligned)
#define WXHSZ 13056   // 48 * WXSTR * 2 bytes
#define NFRAG 1536    // 3 row-tiles * 8 kc * 64 lanes, f16x8 each

// ---- ntn_main LDS (dynamic): Wxh | v  = 13668 B -> occupancy VGPR-limited ----
#define V_OFF   WXHSZ
#define SMEM_MAIN (WXHSZ + (72 + 72 + 9) * 4)    // 13668

// ---- prep_all LDS layout (dynamic, 64 KiB) ----
#define PXH_OFF 0
#define PXL_OFF 24576
#define PVH_OFF 49152
#define PVL_OFF 57344
#define SMEM_PREP 65536

#define TWO_LOG2E 2.8853900817779268f
#define C1F (0.0625f * TWO_LOG2E)

__device__ __forceinline__ f32x4 mfma16(f16x8 a, f16x8 b, f32x4 c) {
    return __builtin_amdgcn_mfma_f32_16x16x32_f16(a, b, c, 0, 0, 0);
}

// Merged prep: blocks [0,256) pack W -> B-frag order HI ONLY (scaled by 16);
// blocks [256,1280) split X into fragment-order hi/lo and compute v12 via MFMA.
// Wb is folded into the v2 row:  v2'[k,m] = (V2w[k]+Wb[k]).x_m + V2b[k].
__global__ __launch_bounds__(256) void prep_all(
    const float* __restrict__ W, f16x8* __restrict__ WfH,
    const float* __restrict__ texts, f16x8* __restrict__ XfH, f16x8* __restrict__ XfL,
    const float* __restrict__ V1w, const float* __restrict__ V1b,
    const float* __restrict__ V2w, const float* __restrict__ V2b,
    const float* __restrict__ Wb, float* __restrict__ v12)
{
    extern __shared__ char psmem[];
    const int blk = blockIdx.x;
    const int t = threadIdx.x;

    if (blk < 256) {   // ---- W fragment pack (hi only) ----
        int idx = blk * 256 + t;       // 65536 total
        int dox = idx & 31;
        int c   = (idx >> 5) & 255;
        int k   = idx >> 13;
        const float* src = W + ((size_t)(k * 256 + c)) * 256 + dox * 8;
        float4 a = *(const float4*)src;
        float4 b = *(const float4*)(src + 4);
        float v[8] = {a.x, a.y, a.z, a.w, b.x, b.y, b.z, b.w};
        f16x8 hi;
        #pragma unroll
        for (int j = 0; j < 8; ++j) hi[j] = (f16)(v[j] * 16.0f);
        int kc = dox >> 2, qd = dox & 3, ct = c >> 4;
        int fr = ((k * 16 + ct) * 8 + kc) * 64 + qd * 16 + (c & 15);
        WfH[fr] = hi;
        return;
    }

    // ---- X fragment pack + v12 via MFMA ----
    f16x8* XsH = (f16x8*)(psmem + PXH_OFF);
    f16x8* XsL = (f16x8*)(psmem + PXL_OFF);
    f16x8* VfH = (f16x8*)(psmem + PVH_OFF);
    f16x8* VfL = (f16x8*)(psmem + PVL_OFF);

    const int b = blk - 256;
    const float* xb = texts + (size_t)b * NF * ED;

    // V fragments: col = which*8 + k at lane&15; scaled by 16; Wb folded into V2
    #pragma unroll
    for (int i0 = 0; i0 < 2; ++i0) {
        int i = t + i0 * 256;          // [0,512)
        int kc = (i >> 6) & 7, lane = i & 63;
        int q = lane >> 4, col = lane & 15;
        int which = col >> 3, kk = col & 7;
        const float* src  = (which ? V2w : V1w) + kk * 256 + kc * 32 + q * 8;
        const float* srcb = Wb + kk * 256 + kc * 32 + q * 8;
        f16x8 hi, lo;
        #pragma unroll
        for (int j = 0; j < 8; ++j) {
            float sv = src[j] + (which ? srcb[j] : 0.f);
            sv *= 16.0f;
            f16 h = (f16)sv;
            hi[j] = h;
            lo[j] = (f16)(sv - (float)h);
        }
        VfH[i] = hi;
        VfL[i] = lo;
    }

    // X fragments: direct global gather (R0 path)
    #pragma unroll
    for (int i0 = 0; i0 < 6; ++i0) {
        int i = t + i0 * 256;          // [0,1536)
        int rt = i >> 9, kc = (i >> 6) & 7, lane = i & 63;
        int q = lane >> 4, l15 = lane & 15;
        int row = rt * 16 + l15;
        f16x8 hi, lo;
        if (row < NF) {
            const float* s = xb + row * ED + kc * 32 + q * 8;
            float4 a = *(const float4*)s;
            float4 c = *(const float4*)(s + 4);
            float v[8] = {a.x, a.y, a.z, a.w, c.x, c.y, c.z, c.w};
            #pragma unroll
            for (int j = 0; j < 8; ++j) {
                f16 h = (f16)v[j];
                hi[j] = h;
                lo[j] = (f16)(v[j] - (float)h);
            }
        } else {
            #pragma unroll
            for (int j = 0; j < 8; ++j) { hi[j] = (f16)0.f; lo[j] = (f16)0.f; }
        }
        XsH[i] = hi;
        XsL[i] = lo;
        XfH[(size_t)b * NFRAG + i] = hi;
        XfL[(size_t)b * NFRAG + i] = lo;
    }
    __syncthreads();

    // v12 MFMA: wave w (<3) handles row-tile rt=w
    const int wave = t >> 6, lane = t & 63;
    const int q = lane >> 4, l15 = lane & 15;
    if (wave < 3) {
        f32x4 acc = (f32x4){0.f, 0.f, 0.f, 0.f};
        #pragma unroll
        for (int kc = 0; kc < 8; ++kc) {
            f16x8 ah = XsH[(wave * 8 + kc) * 64 + lane];
            f16x8 al = XsL[(wave * 8 + kc) * 64 + lane];
            f16x8 bh = VfH[kc * 64 + lane];
            f16x8 bl = VfL[kc * 64 + lane];
            acc = mfma16(ah, bh, acc);
            acc = mfma16(ah, bl, acc);
            acc = mfma16(al, bh, acc);
        }
        const int which = l15 >> 3, kk = l15 & 7;
        const float bias = which ? V2b[kk] : V1b[kk];
        #pragma unroll
        for (int r = 0; r < 4; ++r) {
            const int n = wave * 16 + q * 4 + r;
            if (n < NF)
                v12[((size_t)b * 16 + l15) * NF + n] = acc[r] * 0.0625f + bias;
        }
    }
}

// k-pair merged main (R1 structure), X-hi AND X-lo both read from global
// (L1/L2-resident, XCD-swizzled); LDS holds only Wxh + v -> 13.7 KB, so
// occupancy is VGPR-limited: __launch_bounds__(256,6) -> 24 waves/CU target.
// Wxh stays *16-scaled (exact in f16); 0.0625*2*log2e folded into epilogue fma.
__global__ __launch_bounds__(256, 6) void ntn_main(
    const f16x8* __restrict__ XfHG, const f16x8* __restrict__ XfLG,
    const f16x8* __restrict__ WfH,
    const float* __restrict__ v12,
    const float* __restrict__ Uw, const float* __restrict__ Ubp,
    float* __restrict__ logits)
{
    extern __shared__ char smem[];
    f16*   Wxh  = (f16*)smem;
    float* v1s2 = (float*)(smem + V_OFF);      // [2][36], pre-scaled by 2*log2e
    float* v2s2 = v1s2 + 72;                   // [2][36]
    float* Uws  = v1s2 + 144;                  // [9]

    // XCD swizzle: the 4 k-pair blocks of a given b share id&7 (same XCD)
    const int id  = blockIdx.x;
    const int xcd = id & 7;
    const int rem = id >> 3;
    const int kp  = rem & 3;
    const int b   = ((rem >> 2) << 3) | xcd;
    const int k0  = kp * 2;

    const int t    = threadIdx.x;
    const int wave = t >> 6;
    const int lane = t & 63;
    const int quad = lane >> 4;
    const int l15  = lane & 15;

    const f16x8* Xhg = XfHG + (size_t)b * NFRAG;   // X-hi: global (L1/L2)
    const f16x8* Xlg = XfLG + (size_t)b * NFRAG;   // X-lo: global (L1/L2)

    if (t < 144) {
        const int r = t / 36, n = t - r * 36;
        const int which = r & 1, kq = r >> 1;
        float v = v12[((size_t)b * 16 + which * 8 + (k0 + kq)) * NF + n] * TWO_LOG2E;
        (which ? v2s2 : v1s2)[kq * 36 + n] = v;
    }
    if (t < 8) Uws[t] = Uw[t];
    if (t == 8) Uws[8] = Ubp[0];
    __syncthreads();

    const f16x8* Wk0 = WfH + (size_t)k0 * 8192;   // 16ct*8kc*64
    const f16x8* Wk1 = Wk0 + 8192;

    f32x4 sacc[2][3];
    #pragma unroll
    for (int kk = 0; kk < 2; ++kk)
        #pragma unroll
        for (int it = 0; it < 3; ++it) sacc[kk][it] = (f32x4){0.f, 0.f, 0.f, 0.f};

    for (int h = 0; h < 2; ++h) {
        // ===== phase 1: Wx[:, half h] for BOTH k's; X loads shared =====
        f32x4 acc[3][2][2];   // [rt][ctslot][kk]
        #pragma unroll
        for (int i = 0; i < 3; ++i)
            #pragma unroll
            for (int j = 0; j < 2; ++j) {
                acc[i][j][0] = (f32x4){0.f, 0.f, 0.f, 0.f};
                acc[i][j][1] = (f32x4){0.f, 0.f, 0.f, 0.f};
            }
        const int ct0 = h * 8 + wave;
        const int ct1 = ct0 + 4;
        #pragma unroll 2
        for (int kc = 0; kc < 8; ++kc) {
            f16x8 w00 = Wk0[(ct0 * 8 + kc) * 64 + lane];
            f16x8 w01 = Wk0[(ct1 * 8 + kc) * 64 + lane];
            f16x8 w10 = Wk1[(ct0 * 8 + kc) * 64 + lane];
            f16x8 w11 = Wk1[(ct1 * 8 + kc) * 64 + lane];
            #pragma unroll
            for (int rt = 0; rt < 3; ++rt) {
                f16x8 ah = Xhg[(rt * 8 + kc) * 64 + lane];   // global (L1/L2)
                f16x8 al = Xlg[(rt * 8 + kc) * 64 + lane];   // global (L1/L2)
                acc[rt][0][0] = mfma16(ah, w00, acc[rt][0][0]);
                acc[rt][0][0] = mfma16(al, w00, acc[rt][0][0]);
                acc[rt][1][0] = mfma16(ah, w01, acc[rt][1][0]);
                acc[rt][1][0] = mfma16(al, w01, acc[rt][1][0]);
                acc[rt][0][1] = mfma16(ah, w10, acc[rt][0][1]);
                acc[rt][0][1] = mfma16(al, w10, acc[rt][0][1]);
                acc[rt][1][1] = mfma16(ah, w11, acc[rt][1][1]);
                acc[rt][1][1] = mfma16(al, w11, acc[rt][1][1]);
            }
        }
        // ===== per-k sequential: store Wxh (scaled) -> phase 2 =====
        #pragma unroll
        for (int kk = 0; kk < 2; ++kk) {
            __syncthreads();   // previous Wxh readers done
            #pragma unroll
            for (int rt = 0; rt < 3; ++rt)
                #pragma unroll
                for (int j2 = 0; j2 < 2; ++j2) {
                    const int cl = (j2 ? (wave + 4) : wave) * 16 + l15;
                    #pragma unroll
                    for (int r = 0; r < 4; ++r) {
                        const int row = rt * 16 + quad * 4 + r;
                        Wxh[row * WXSTR + cl] = (f16)(acc[rt][j2][kk][r]);
                    }
                }
            __syncthreads();
            // phase 2: S_kk += Wxh * (Xh + Xl)^T (9 tiles over 4 waves)
            #pragma unroll
            for (int it = 0; it < 3; ++it) {
                const int p = wave + it * 4;
                if (p < 9) {
                    const int nt = p / 3, mt = p % 3;
                    const f16* wxh_p = Wxh + (nt * 16 + l15) * WXSTR + quad * 8;
                    #pragma unroll
                    for (int kc2 = 0; kc2 < 4; ++kc2) {
                        f16x8 pah = *(const f16x8*)(wxh_p + kc2 * 32);
                        f16x8 pbh = Xhg[(mt * 8 + h * 4 + kc2) * 64 + lane];
                        f16x8 pbl = Xlg[(mt * 8 + h * 4 + kc2) * 64 + lane];
                        sacc[kk][it] = mfma16(pah, pbh, sacc[kk][it]);
                        sacc[kk][it] = mfma16(pah, pbl, sacc[kk][it]);
                    }
                }
            }
        }
    }

    // ===== epilogue: T = tanh(S + v1 + v2) for both k -> Ts (overlays Wxh) =====
    __syncthreads();
    float* Ts = (float*)Wxh;   // 2*1296 f32 = 10368 B <= 13056 B
    #pragma unroll
    for (int kk = 0; kk < 2; ++kk)
        #pragma unroll
        for (int it = 0; it < 3; ++it) {
            const int p = wave + it * 4;
            if (p < 9) {
                const int nt = p / 3, mt = p % 3;
                const int m = mt * 16 + l15;
                if (m < NF) {
                    #pragma unroll
                    for (int r = 0; r < 4; ++r) {
                        const int n = nt * 16 + quad * 4 + r;
                        if (n < NF) {
                            // x = 2*log2e * (S + v1 + v2); S = sacc * 0.0625
                            float x = sacc[kk][it][r] * C1F
                                      + v1s2[kk * 36 + n] + v2s2[kk * 36 + m];
                            float e = exp2f(x);
                            Ts[kk * NN2 + n * NF + m] = 1.f - 2.f / (e + 1.f);
                        }
                    }
                }
            }
        }
    __syncthreads();
    #pragma unroll
    for (int u0 = 0; u0 < 2; ++u0) {
        const int u = t + u0 * 256;
        if (u < 2 * QPK) {
            const int kk = (u >= QPK);
            const int tt = u - kk * QPK;
            const float* tp = Ts + kk * NN2 + tt * 8;
            float lg = Uws[8];
            #pragma unroll
            for (int j = 0; j < 8; ++j) lg += Uws[j] * tp[j];
            logits[(size_t)b * NN2 + (k0 + kk) * QPK + tt] = lg;
        }
    }
}

// ---- in-place row softmax: 4 rows per 256-thread block (one per wave) ----
__global__ __launch_bounds__(256) void softmax_rows(float* __restrict__ out) {
    int row = blockIdx.x * 4 + (threadIdx.x >> 6);
    int t = threadIdx.x & 63;
    float* p = out + (size_t)row * NF;
    float v = (t < NF) ? p[t] : -INFINITY;
    float mx = v;
    #pragma unroll
    for (int off = 32; off > 0; off >>= 1) mx = fmaxf(mx, __shfl_xor(mx, off));
    float e = (t < NF) ? __expf(v - mx) : 0.f;
    float sm = e;
    #pragma unroll
    for (int off = 32; off > 0; off >>= 1) sm += __shfl_xor(sm, off);
    if (t < NF) p[t] = e / sm;
}

extern "C" void kernel_launch(void* const* d_in, const int* in_sizes, int n_in,
                              void* d_out, int out_size, void* d_ws, size_t ws_size,
                              hipStream_t stream) {
    const float* texts = (const float*)d_in[0];
    const float* W     = (const float*)d_in[1];
    const float* Wb    = (const float*)d_in[2];
    const float* V1w   = (const float*)d_in[3];
    const float* V1b   = (const float*)d_in[4];
    const float* V2w   = (const float*)d_in[5];
    const float* V2b   = (const float*)d_in[6];
    const float* Uw    = (const float*)d_in[7];
    const float* Ub    = (const float*)d_in[8];

    char* ws = (char*)d_ws;
    f16x8* WfH = (f16x8*)ws;                                   //  1 MiB
    f16x8* XfH = (f16x8*)(ws + (1 << 20));                     // 24 MiB
    f16x8* XfL = (f16x8*)(ws + (1 << 20) + (size_t)NB * NFRAG * 16);       // 24 MiB
    float* v12 = (float*)(ws + (1 << 20) + (size_t)2 * NB * NFRAG * 16);   // 2.25 MiB
    float* logits = (float*)d_out;

    hipFuncSetAttribute((const void*)prep_all,
                        hipFuncAttributeMaxDynamicSharedMemorySize, SMEM_PREP);
    hipFuncSetAttribute((const void*)ntn_main,
                        hipFuncAttributeMaxDynamicSharedMemorySize, SMEM_MAIN);

    prep_all<<<256 + NB, 256, SMEM_PREP, stream>>>(W, WfH, texts, XfH, XfL,
                                                   V1w, V1b, V2w, V2b, Wb, v12);
    ntn_main<<<NB * NK / 2, 256, SMEM_MAIN, stream>>>(XfH, XfL, WfH, v12, Uw, Ub, logits);
    softmax_rows<<<NB * NF / 4, 256, 0, stream>>>(logits);
}

// Round 4
// 257.929 us; speedup vs baseline: 2.1536x; 2.1536x over previous
//
#include <hip/hip_runtime.h>
#include <math.h>

#define NB 1024
#define NF 36
#define ED 256
#define NK 8
#define NN2 1296   // 36*36
#define QPK 162    // 1296/8

typedef _Float16 f16;
typedef f16 f16x8 __attribute__((ext_vector_type(8)));
typedef float f32x4 __attribute__((ext_vector_type(4)));

#define WXSTR 136     // f16 per Wx half-row (128 + 8 pad); 272B = 17*16 (b128-aligned)
#define WXHSZ 13056   // 48 * WXSTR * 2 bytes
#define NFRAG 1536    // 3 row-tiles * 8 kc * 64 lanes, f16x8 each

// ---- ntn_main LDS (dynamic): Wxh | v  = 13668 B ----
// Occupancy: VGPR-limited. launch_bounds min-waves stays at 4 (VGPR budget 128)
// -- demanding 6 forced the allocator to 80 regs and spilled the accumulators
// (R2/R3: VGPR=40 + 1.9 GB scratch traffic). With ~64 actual VGPRs the HW
// schedules up to 8 blocks/CU on its own (LDS 8*13.7KB=109KB < 160KB).
#define V_OFF   WXHSZ
#define SMEM_MAIN (WXHSZ + (72 + 72 + 9) * 4)    // 13668

// ---- prep_all LDS layout (dynamic, 64 KiB) ----
#define PXH_OFF 0
#define PXL_OFF 24576
#define PVH_OFF 49152
#define PVL_OFF 57344
#define SMEM_PREP 65536

#define TWO_LOG2E 2.8853900817779268f
#define C1F (0.0625f * TWO_LOG2E)

__device__ __forceinline__ f32x4 mfma16(f16x8 a, f16x8 b, f32x4 c) {
    return __builtin_amdgcn_mfma_f32_16x16x32_f16(a, b, c, 0, 0, 0);
}

// Merged prep: blocks [0,256) pack W -> B-frag order HI ONLY (scaled by 16);
// blocks [256,1280) split X into fragment-order hi/lo and compute v12 via MFMA.
// Wb is folded into the v2 row:  v2'[k,m] = (V2w[k]+Wb[k]).x_m + V2b[k].
__global__ __launch_bounds__(256) void prep_all(
    const float* __restrict__ W, f16x8* __restrict__ WfH,
    const float* __restrict__ texts, f16x8* __restrict__ XfH, f16x8* __restrict__ XfL,
    const float* __restrict__ V1w, const float* __restrict__ V1b,
    const float* __restrict__ V2w, const float* __restrict__ V2b,
    const float* __restrict__ Wb, float* __restrict__ v12)
{
    extern __shared__ char psmem[];
    const int blk = blockIdx.x;
    const int t = threadIdx.x;

    if (blk < 256) {   // ---- W fragment pack (hi only) ----
        int idx = blk * 256 + t;       // 65536 total
        int dox = idx & 31;
        int c   = (idx >> 5) & 255;
        int k   = idx >> 13;
        const float* src = W + ((size_t)(k * 256 + c)) * 256 + dox * 8;
        float4 a = *(const float4*)src;
        float4 b = *(const float4*)(src + 4);
        float v[8] = {a.x, a.y, a.z, a.w, b.x, b.y, b.z, b.w};
        f16x8 hi;
        #pragma unroll
        for (int j = 0; j < 8; ++j) hi[j] = (f16)(v[j] * 16.0f);
        int kc = dox >> 2, qd = dox & 3, ct = c >> 4;
        int fr = ((k * 16 + ct) * 8 + kc) * 64 + qd * 16 + (c & 15);
        WfH[fr] = hi;
        return;
    }

    // ---- X fragment pack + v12 via MFMA ----
    f16x8* XsH = (f16x8*)(psmem + PXH_OFF);
    f16x8* XsL = (f16x8*)(psmem + PXL_OFF);
    f16x8* VfH = (f16x8*)(psmem + PVH_OFF);
    f16x8* VfL = (f16x8*)(psmem + PVL_OFF);

    const int b = blk - 256;
    const float* xb = texts + (size_t)b * NF * ED;

    // V fragments: col = which*8 + k at lane&15; scaled by 16; Wb folded into V2
    #pragma unroll
    for (int i0 = 0; i0 < 2; ++i0) {
        int i = t + i0 * 256;          // [0,512)
        int kc = (i >> 6) & 7, lane = i & 63;
        int q = lane >> 4, col = lane & 15;
        int which = col >> 3, kk = col & 7;
        const float* src  = (which ? V2w : V1w) + kk * 256 + kc * 32 + q * 8;
        const float* srcb = Wb + kk * 256 + kc * 32 + q * 8;
        f16x8 hi, lo;
        #pragma unroll
        for (int j = 0; j < 8; ++j) {
            float sv = src[j] + (which ? srcb[j] : 0.f);
            sv *= 16.0f;
            f16 h = (f16)sv;
            hi[j] = h;
            lo[j] = (f16)(sv - (float)h);
        }
        VfH[i] = hi;
        VfL[i] = lo;
    }

    // X fragments: direct global gather (R0 path)
    #pragma unroll
    for (int i0 = 0; i0 < 6; ++i0) {
        int i = t + i0 * 256;          // [0,1536)
        int rt = i >> 9, kc = (i >> 6) & 7, lane = i & 63;
        int q = lane >> 4, l15 = lane & 15;
        int row = rt * 16 + l15;
        f16x8 hi, lo;
        if (row < NF) {
            const float* s = xb + row * ED + kc * 32 + q * 8;
            float4 a = *(const float4*)s;
            float4 c = *(const float4*)(s + 4);
            float v[8] = {a.x, a.y, a.z, a.w, c.x, c.y, c.z, c.w};
            #pragma unroll
            for (int j = 0; j < 8; ++j) {
                f16 h = (f16)v[j];
                hi[j] = h;
                lo[j] = (f16)(v[j] - (float)h);
            }
        } else {
            #pragma unroll
            for (int j = 0; j < 8; ++j) { hi[j] = (f16)0.f; lo[j] = (f16)0.f; }
        }
        XsH[i] = hi;
        XsL[i] = lo;
        XfH[(size_t)b * NFRAG + i] = hi;
        XfL[(size_t)b * NFRAG + i] = lo;
    }
    __syncthreads();

    // v12 MFMA: wave w (<3) handles row-tile rt=w
    const int wave = t >> 6, lane = t & 63;
    const int q = lane >> 4, l15 = lane & 15;
    if (wave < 3) {
        f32x4 acc = (f32x4){0.f, 0.f, 0.f, 0.f};
        #pragma unroll
        for (int kc = 0; kc < 8; ++kc) {
            f16x8 ah = XsH[(wave * 8 + kc) * 64 + lane];
            f16x8 al = XsL[(wave * 8 + kc) * 64 + lane];
            f16x8 bh = VfH[kc * 64 + lane];
            f16x8 bl = VfL[kc * 64 + lane];
            acc = mfma16(ah, bh, acc);
            acc = mfma16(ah, bl, acc);
            acc = mfma16(al, bh, acc);
        }
        const int which = l15 >> 3, kk = l15 & 7;
        const float bias = which ? V2b[kk] : V1b[kk];
        #pragma unroll
        for (int r = 0; r < 4; ++r) {
            const int n = wave * 16 + q * 4 + r;
            if (n < NF)
                v12[((size_t)b * 16 + l15) * NF + n] = acc[r] * 0.0625f + bias;
        }
    }
}

// k-pair merged main (R1 structure), X-hi AND X-lo both read from global
// (L1/L2-resident, XCD-swizzled); LDS holds only Wxh + v -> 13.7 KB.
// Wxh stays *16-scaled (exact in f16); 0.0625*2*log2e folded into epilogue fma.
__global__ __launch_bounds__(256, 4) void ntn_main(
    const f16x8* __restrict__ XfHG, const f16x8* __restrict__ XfLG,
    const f16x8* __restrict__ WfH,
    const float* __restrict__ v12,
    const float* __restrict__ Uw, const float* __restrict__ Ubp,
    float* __restrict__ logits)
{
    extern __shared__ char smem[];
    f16*   Wxh  = (f16*)smem;
    float* v1s2 = (float*)(smem + V_OFF);      // [2][36], pre-scaled by 2*log2e
    float* v2s2 = v1s2 + 72;                   // [2][36]
    float* Uws  = v1s2 + 144;                  // [9]

    // XCD swizzle: the 4 k-pair blocks of a given b share id&7 (same XCD)
    const int id  = blockIdx.x;
    const int xcd = id & 7;
    const int rem = id >> 3;
    const int kp  = rem & 3;
    const int b   = ((rem >> 2) << 3) | xcd;
    const int k0  = kp * 2;

    const int t    = threadIdx.x;
    const int wave = t >> 6;
    const int lane = t & 63;
    const int quad = lane >> 4;
    const int l15  = lane & 15;

    const f16x8* Xhg = XfHG + (size_t)b * NFRAG;   // X-hi: global (L1/L2)
    const f16x8* Xlg = XfLG + (size_t)b * NFRAG;   // X-lo: global (L1/L2)

    if (t < 144) {
        const int r = t / 36, n = t - r * 36;
        const int which = r & 1, kq = r >> 1;
        float v = v12[((size_t)b * 16 + which * 8 + (k0 + kq)) * NF + n] * TWO_LOG2E;
        (which ? v2s2 : v1s2)[kq * 36 + n] = v;
    }
    if (t < 8) Uws[t] = Uw[t];
    if (t == 8) Uws[8] = Ubp[0];
    __syncthreads();

    const f16x8* Wk0 = WfH + (size_t)k0 * 8192;   // 16ct*8kc*64
    const f16x8* Wk1 = Wk0 + 8192;

    f32x4 sacc[2][3];
    #pragma unroll
    for (int kk = 0; kk < 2; ++kk)
        #pragma unroll
        for (int it = 0; it < 3; ++it) sacc[kk][it] = (f32x4){0.f, 0.f, 0.f, 0.f};

    for (int h = 0; h < 2; ++h) {
        // ===== phase 1: Wx[:, half h] for BOTH k's; X loads shared =====
        f32x4 acc[3][2][2];   // [rt][ctslot][kk]
        #pragma unroll
        for (int i = 0; i < 3; ++i)
            #pragma unroll
            for (int j = 0; j < 2; ++j) {
                acc[i][j][0] = (f32x4){0.f, 0.f, 0.f, 0.f};
                acc[i][j][1] = (f32x4){0.f, 0.f, 0.f, 0.f};
            }
        const int ct0 = h * 8 + wave;
        const int ct1 = ct0 + 4;
        #pragma unroll 2
        for (int kc = 0; kc < 8; ++kc) {
            f16x8 w00 = Wk0[(ct0 * 8 + kc) * 64 + lane];
            f16x8 w01 = Wk0[(ct1 * 8 + kc) * 64 + lane];
            f16x8 w10 = Wk1[(ct0 * 8 + kc) * 64 + lane];
            f16x8 w11 = Wk1[(ct1 * 8 + kc) * 64 + lane];
            #pragma unroll
            for (int rt = 0; rt < 3; ++rt) {
                f16x8 ah = Xhg[(rt * 8 + kc) * 64 + lane];   // global (L1/L2)
                f16x8 al = Xlg[(rt * 8 + kc) * 64 + lane];   // global (L1/L2)
                acc[rt][0][0] = mfma16(ah, w00, acc[rt][0][0]);
                acc[rt][0][0] = mfma16(al, w00, acc[rt][0][0]);
                acc[rt][1][0] = mfma16(ah, w01, acc[rt][1][0]);
                acc[rt][1][0] = mfma16(al, w01, acc[rt][1][0]);
                acc[rt][0][1] = mfma16(ah, w10, acc[rt][0][1]);
                acc[rt][0][1] = mfma16(al, w10, acc[rt][0][1]);
                acc[rt][1][1] = mfma16(ah, w11, acc[rt][1][1]);
                acc[rt][1][1] = mfma16(al, w11, acc[rt][1][1]);
            }
        }
        // ===== per-k sequential: store Wxh (scaled) -> phase 2 =====
        #pragma unroll
        for (int kk = 0; kk < 2; ++kk) {
            __syncthreads();   // previous Wxh readers done
            #pragma unroll
            for (int rt = 0; rt < 3; ++rt)
                #pragma unroll
                for (int j2 = 0; j2 < 2; ++j2) {
                    const int cl = (j2 ? (wave + 4) : wave) * 16 + l15;
                    #pragma unroll
                    for (int r = 0; r < 4; ++r) {
                        const int row = rt * 16 + quad * 4 + r;
                        Wxh[row * WXSTR + cl] = (f16)(acc[rt][j2][kk][r]);
                    }
                }
            __syncthreads();
            // phase 2: S_kk += Wxh * (Xh + Xl)^T (9 tiles over 4 waves)
            #pragma unroll
            for (int it = 0; it < 3; ++it) {
                const int p = wave + it * 4;
                if (p < 9) {
                    const int nt = p / 3, mt = p % 3;
                    const f16* wxh_p = Wxh + (nt * 16 + l15) * WXSTR + quad * 8;
                    #pragma unroll
                    for (int kc2 = 0; kc2 < 4; ++kc2) {
                        f16x8 pah = *(const f16x8*)(wxh_p + kc2 * 32);
                        f16x8 pbh = Xhg[(mt * 8 + h * 4 + kc2) * 64 + lane];
                        f16x8 pbl = Xlg[(mt * 8 + h * 4 + kc2) * 64 + lane];
                        sacc[kk][it] = mfma16(pah, pbh, sacc[kk][it]);
                        sacc[kk][it] = mfma16(pah, pbl, sacc[kk][it]);
                    }
                }
            }
        }
    }

    // ===== epilogue: T = tanh(S + v1 + v2) for both k -> Ts (overlays Wxh) =====
    __syncthreads();
    float* Ts = (float*)Wxh;   // 2*1296 f32 = 10368 B <= 13056 B
    #pragma unroll
    for (int kk = 0; kk < 2; ++kk)
        #pragma unroll
        for (int it = 0; it < 3; ++it) {
            const int p = wave + it * 4;
            if (p < 9) {
                const int nt = p / 3, mt = p % 3;
                const int m = mt * 16 + l15;
                if (m < NF) {
                    #pragma unroll
                    for (int r = 0; r < 4; ++r) {
                        const int n = nt * 16 + quad * 4 + r;
                        if (n < NF) {
                            // x = 2*log2e * (S + v1 + v2); S = sacc * 0.0625
                            float x = sacc[kk][it][r] * C1F
                                      + v1s2[kk * 36 + n] + v2s2[kk * 36 + m];
                            float e = exp2f(x);
                            Ts[kk * NN2 + n * NF + m] = 1.f - 2.f / (e + 1.f);
                        }
                    }
                }
            }
        }
    __syncthreads();
    #pragma unroll
    for (int u0 = 0; u0 < 2; ++u0) {
        const int u = t + u0 * 256;
        if (u < 2 * QPK) {
            const int kk = (u >= QPK);
            const int tt = u - kk * QPK;
            const float* tp = Ts + kk * NN2 + tt * 8;
            float lg = Uws[8];
            #pragma unroll
            for (int j = 0; j < 8; ++j) lg += Uws[j] * tp[j];
            logits[(size_t)b * NN2 + (k0 + kk) * QPK + tt] = lg;
        }
    }
}

// ---- in-place row softmax: 4 rows per 256-thread block (one per wave) ----
__global__ __launch_bounds__(256) void softmax_rows(float* __restrict__ out) {
    int row = blockIdx.x * 4 + (threadIdx.x >> 6);
    int t = threadIdx.x & 63;
    float* p = out + (size_t)row * NF;
    float v = (t < NF) ? p[t] : -INFINITY;
    float mx = v;
    #pragma unroll
    for (int off = 32; off > 0; off >>= 1) mx = fmaxf(mx, __shfl_xor(mx, off));
    float e = (t < NF) ? __expf(v - mx) : 0.f;
    float sm = e;
    #pragma unroll
    for (int off = 32; off > 0; off >>= 1) sm += __shfl_xor(sm, off);
    if (t < NF) p[t] = e / sm;
}

extern "C" void kernel_launch(void* const* d_in, const int* in_sizes, int n_in,
                              void* d_out, int out_size, void* d_ws, size_t ws_size,
                              hipStream_t stream) {
    const float* texts = (const float*)d_in[0];
    const float* W     = (const float*)d_in[1];
    const float* Wb    = (const float*)d_in[2];
    const float* V1w   = (const float*)d_in[3];
    const float* V1b   = (const float*)d_in[4];
    const float* V2w   = (const float*)d_in[5];
    const float* V2b   = (const float*)d_in[6];
    const float* Uw    = (const float*)d_in[7];
    const float* Ub    = (const float*)d_in[8];

    char* ws = (char*)d_ws;
    f16x8* WfH = (f16x8*)ws;                                   //  1 MiB
    f16x8* XfH = (f16x8*)(ws + (1 << 20));                     // 24 MiB
    f16x8* XfL = (f16x8*)(ws + (1 << 20) + (size_t)NB * NFRAG * 16);       // 24 MiB
    float* v12 = (float*)(ws + (1 << 20) + (size_t)2 * NB * NFRAG * 16);   // 2.25 MiB
    float* logits = (float*)d_out;

    hipFuncSetAttribute((const void*)prep_all,
                        hipFuncAttributeMaxDynamicSharedMemorySize, SMEM_PREP);
    hipFuncSetAttribute((const void*)ntn_main,
                        hipFuncAttributeMaxDynamicSharedMemorySize, SMEM_MAIN);

    prep_all<<<256 + NB, 256, SMEM_PREP, stream>>>(W, WfH, texts, XfH, XfL,
                                                   V1w, V1b, V2w, V2b, Wb, v12);
    ntn_main<<<NB * NK / 2, 256, SMEM_MAIN, stream>>>(XfH, XfL, WfH, v12, Uw, Ub, logits);
    softmax_rows<<<NB * NF / 4, 256, 0, stream>>>(logits);
}

// Round 5
// 234.327 us; speedup vs baseline: 2.3705x; 1.1007x over previous
//
#include <hip/hip_runtime.h>
#include <math.h>

#define NB 1024
#define NF 36
#define ED 256
#define NK 8
#define NN2 1296   // 36*36
#define QPK 162    // 1296/8

typedef _Float16 f16;
typedef f16 f16x8 __attribute__((ext_vector_type(8)));
typedef float f32x4 __attribute__((ext_vector_type(4)));

#define WXSTR 136     // f16 per Wx half-row (128 + 8 pad); 272B = 17*16 (b128-aligned)
#define WXHSZ 13056   // 48 * WXSTR * 2 bytes
#define NFRAG 1536    // 3 row-tiles * 8 kc * 64 lanes, f16x8 each

// ---- ntn_main LDS: Xh | Wxh/Ts | v1 v2 Uw L  = 39540 B -> 4 blocks/CU ----
#define XH_OFF  0
#define WXH_OFF 24576
#define V_OFF   (24576 + WXHSZ)                  // 37632
#define SMEM_MAIN (V_OFF + (72 + 72 + 9 + 324) * 4)   // 39540; 4x = 158160 <= 163840

// ---- prep_all LDS: VfH | VfL | partials  = 28672 B -> 5 blocks/CU ----
// (W-pack blocks overlay a [16][264] f16 tile = 8448 B in the same region)
#define PVH_OFF 0
#define PVL_OFF 8192
#define PP_OFF  16384
#define SMEM_PREP 28672

#define TWO_LOG2E 2.8853900817779268f
#define C1F (0.0625f * TWO_LOG2E)

__device__ __forceinline__ f32x4 mfma16(f16x8 a, f16x8 b, f32x4 c) {
    return __builtin_amdgcn_mfma_f32_16x16x32_f16(a, b, c, 0, 0, 0);
}

// blocks [0,128): W fragment pack, one (k,ct) tile per block.
//   coalesced 16KB read -> LDS transpose -> coalesced 8KB write (was: 64
//   scattered 16B stores per wave).
// blocks [128,1152): X fragment pack (register-resident) + v12 via per-wave
//   kc-partial MFMAs + LDS reduction (no 48KB X staging; 28KB total LDS).
// Wb is folded into the v2 row: v2'[k,m] = (V2w[k]+Wb[k]).x_m + V2b[k].
__global__ __launch_bounds__(256, 4) void prep_all(
    const float* __restrict__ W, f16x8* __restrict__ WfH,
    const float* __restrict__ texts, f16x8* __restrict__ XfH, f16x8* __restrict__ XfL,
    const float* __restrict__ V1w, const float* __restrict__ V1b,
    const float* __restrict__ V2w, const float* __restrict__ V2b,
    const float* __restrict__ Wb, float* __restrict__ v12)
{
    extern __shared__ char psmem[];
    const int blk = blockIdx.x;
    const int t = threadIdx.x;
    const int wave = t >> 6, lane = t & 63;

    if (blk < 128) {   // ---- W pack: (k, ct) tile ----
        const int k = blk >> 4, ct = blk & 15;
        f16* Wl = (f16*)psmem;                    // [16][264] f16, scaled x16
        {
            const int r = t >> 4, seg = t & 15;   // row in tile, 16-float segment
            const float* src = W + ((size_t)(k * 256 + ct * 16 + r)) * 256 + seg * 16;
            f16* d = Wl + r * 264 + seg * 16;
            #pragma unroll
            for (int j4 = 0; j4 < 4; ++j4) {
                float4 a = ((const float4*)src)[j4];
                d[j4 * 4 + 0] = (f16)(a.x * 16.0f);
                d[j4 * 4 + 1] = (f16)(a.y * 16.0f);
                d[j4 * 4 + 2] = (f16)(a.z * 16.0f);
                d[j4 * 4 + 3] = (f16)(a.w * 16.0f);
            }
        }
        __syncthreads();
        f16x8* dst = WfH + (size_t)(k * 16 + ct) * 8 * 64;
        #pragma unroll
        for (int e0 = 0; e0 < 2; ++e0) {
            const int e = t + e0 * 256;           // [0,512) output entries
            const int kc = e >> 6, el = e & 63, qd = el >> 4, l15 = el & 15;
            dst[e] = *(const f16x8*)(Wl + l15 * 264 + (kc * 4 + qd) * 8);
        }
        return;
    }

    // ---- X fragment pack + v12 ----
    f16x8* VfH = (f16x8*)(psmem + PVH_OFF);
    f16x8* VfL = (f16x8*)(psmem + PVL_OFF);
    f32x4* Pp  = (f32x4*)(psmem + PP_OFF);        // [4 waves][3 rt][64 lanes]

    const int b = blk - 128;
    const float* xb = texts + (size_t)b * NF * ED;

    // V fragments: col = which*8 + k at lane&15; scaled by 16; Wb folded into V2
    #pragma unroll
    for (int i0 = 0; i0 < 2; ++i0) {
        int i = t + i0 * 256;          // [0,512)
        int kc = (i >> 6) & 7, ln = i & 63;
        int q = ln >> 4, col = ln & 15;
        int which = col >> 3, kk = col & 7;
        const float* src  = (which ? V2w : V1w) + kk * 256 + kc * 32 + q * 8;
        const float* srcb = Wb + kk * 256 + kc * 32 + q * 8;
        f16x8 hi, lo;
        #pragma unroll
        for (int j = 0; j < 8; ++j) {
            float sv = src[j] + (which ? srcb[j] : 0.f);
            sv *= 16.0f;
            f16 h = (f16)sv;
            hi[j] = h;
            lo[j] = (f16)(sv - (float)h);
        }
        VfH[i] = hi;
        VfL[i] = lo;
    }

    // X fragments: direct global gather -> registers + global store.
    // frag index for i = t + i0*256 is idx = i0*4 + wave -> this wave owns
    // complete (rt = idx>>3, kc = idx&7) fragments: kc in {wave, wave+4}.
    f16x8 FH[6], FL[6];
    #pragma unroll
    for (int i0 = 0; i0 < 6; ++i0) {
        int i = t + i0 * 256;          // [0,1536)
        int rt = i >> 9, kc = (i >> 6) & 7;
        int q = lane >> 4, l15 = lane & 15;
        int row = rt * 16 + l15;
        f16x8 hi, lo;
        if (row < NF) {
            const float* s = xb + row * ED + kc * 32 + q * 8;
            float4 a = *(const float4*)s;
            float4 c = *(const float4*)(s + 4);
            float v[8] = {a.x, a.y, a.z, a.w, c.x, c.y, c.z, c.w};
            #pragma unroll
            for (int j = 0; j < 8; ++j) {
                f16 h = (f16)v[j];
                hi[j] = h;
                lo[j] = (f16)(v[j] - (float)h);
            }
        } else {
            #pragma unroll
            for (int j = 0; j < 8; ++j) { hi[j] = (f16)0.f; lo[j] = (f16)0.f; }
        }
        FH[i0] = hi;
        FL[i0] = lo;
        XfH[(size_t)b * NFRAG + i] = hi;
        XfL[(size_t)b * NFRAG + i] = lo;
    }
    __syncthreads();   // VfH/VfL staged

    // per-wave kc-partials of v12 (kc = wave and wave+4), all 3 row-tiles
    f32x4 pacc[3];
    #pragma unroll
    for (int rt = 0; rt < 3; ++rt) pacc[rt] = (f32x4){0.f, 0.f, 0.f, 0.f};
    #pragma unroll
    for (int rt = 0; rt < 3; ++rt) {
        #pragma unroll
        for (int s = 0; s < 2; ++s) {
            const int i0 = rt * 2 + s;          // frag (rt, kc = wave + 4*s)
            const int kc = wave + 4 * s;
            f16x8 bh = VfH[kc * 64 + lane];
            f16x8 bl = VfL[kc * 64 + lane];
            pacc[rt] = mfma16(FH[i0], bh, pacc[rt]);
            pacc[rt] = mfma16(FH[i0], bl, pacc[rt]);
            pacc[rt] = mfma16(FL[i0], bh, pacc[rt]);
        }
    }
    #pragma unroll
    for (int rt = 0; rt < 3; ++rt)
        Pp[(wave * 3 + rt) * 64 + lane] = pacc[rt];
    __syncthreads();

    // reduce 4 wave-partials; wave rt (<3) owns row-tile rt
    if (wave < 3) {
        f32x4 acc = Pp[(0 * 3 + wave) * 64 + lane];
        #pragma unroll
        for (int w = 1; w < 4; ++w) acc += Pp[(w * 3 + wave) * 64 + lane];
        const int q = lane >> 4, l15 = lane & 15;
        const int which = l15 >> 3, kk = l15 & 7;
        const float bias = which ? V2b[kk] : V1b[kk];
        #pragma unroll
        for (int r = 0; r < 4; ++r) {
            const int n = wave * 16 + q * 4 + r;
            if (n < NF)
                v12[((size_t)b * 16 + l15) * NF + n] = acc[r] * 0.0625f + bias;
        }
    }
}

// k-pair merged main (R1 structure: Xh staged in LDS, X-lo from global) with
// fused per-block softmax: a k-pair block's 324 logits are exactly 9 complete
// output rows (torch-faithful [K,N,N]->(N*N,K) reshape), so softmax is local.
// Wxh stays *16-scaled (exact in f16); 0.0625*2*log2e folded into epilogue fma.
// Ts stored chunk-padded (8 f32 -> 9) so U-dot reads spread banks (9u mod 32).
__global__ __launch_bounds__(256, 4) void ntn_main(
    const f16x8* __restrict__ XfHG, const f16x8* __restrict__ XfLG,
    const f16x8* __restrict__ WfH,
    const float* __restrict__ v12,
    const float* __restrict__ Uw, const float* __restrict__ Ubp,
    float* __restrict__ out)
{
    extern __shared__ char smem[];
    f16x8* Xh   = (f16x8*)(smem + XH_OFF);
    f16*   Wxh  = (f16*)(smem + WXH_OFF);
    float* v1s2 = (float*)(smem + V_OFF);      // [2][36], pre-scaled by 2*log2e
    float* v2s2 = v1s2 + 72;                   // [2][36]
    float* Uws  = v1s2 + 144;                  // [9]
    float* Ls   = v1s2 + 153;                  // [324] logits

    // XCD swizzle: the 4 k-pair blocks of a given b share id&7 (same XCD)
    const int id  = blockIdx.x;
    const int xcd = id & 7;
    const int rem = id >> 3;
    const int kp  = rem & 3;
    const int b   = ((rem >> 2) << 3) | xcd;
    const int k0  = kp * 2;

    const int t    = threadIdx.x;
    const int wave = t >> 6;
    const int lane = t & 63;
    const int quad = lane >> 4;
    const int l15  = lane & 15;

    const f16x8* Xlg = XfLG + (size_t)b * NFRAG;   // X-lo: global (L2/L1)

    // ---- stage X-hi fragments into LDS (coalesced dwordx4) ----
    {
        const f16x8* gh = XfHG + (size_t)b * NFRAG;
        #pragma unroll
        for (int i = 0; i < 6; ++i) Xh[t + i * 256] = gh[t + i * 256];
    }
    if (t < 144) {
        const int r = t / 36, n = t - r * 36;
        const int which = r & 1, kq = r >> 1;
        float v = v12[((size_t)b * 16 + which * 8 + (k0 + kq)) * NF + n] * TWO_LOG2E;
        (which ? v2s2 : v1s2)[kq * 36 + n] = v;
    }
    if (t < 8) Uws[t] = Uw[t];
    if (t == 8) Uws[8] = Ubp[0];
    __syncthreads();

    const f16x8* Wk0 = WfH + (size_t)k0 * 8192;   // 16ct*8kc*64
    const f16x8* Wk1 = Wk0 + 8192;

    f32x4 sacc[2][3];
    #pragma unroll
    for (int kk = 0; kk < 2; ++kk)
        #pragma unroll
        for (int it = 0; it < 3; ++it) sacc[kk][it] = (f32x4){0.f, 0.f, 0.f, 0.f};

    for (int h = 0; h < 2; ++h) {
        // ===== phase 1: Wx[:, half h] for BOTH k's; X loads shared =====
        f32x4 acc[3][2][2];   // [rt][ctslot][kk]
        #pragma unroll
        for (int i = 0; i < 3; ++i)
            #pragma unroll
            for (int j = 0; j < 2; ++j) {
                acc[i][j][0] = (f32x4){0.f, 0.f, 0.f, 0.f};
                acc[i][j][1] = (f32x4){0.f, 0.f, 0.f, 0.f};
            }
        const int ct0 = h * 8 + wave;
        const int ct1 = ct0 + 4;
        #pragma unroll 2
        for (int kc = 0; kc < 8; ++kc) {
            f16x8 w00 = Wk0[(ct0 * 8 + kc) * 64 + lane];
            f16x8 w01 = Wk0[(ct1 * 8 + kc) * 64 + lane];
            f16x8 w10 = Wk1[(ct0 * 8 + kc) * 64 + lane];
            f16x8 w11 = Wk1[(ct1 * 8 + kc) * 64 + lane];
            #pragma unroll
            for (int rt = 0; rt < 3; ++rt) {
                f16x8 ah = Xh[(rt * 8 + kc) * 64 + lane];    // LDS ds_read_b128
                f16x8 al = Xlg[(rt * 8 + kc) * 64 + lane];   // global (L2/L1)
                acc[rt][0][0] = mfma16(ah, w00, acc[rt][0][0]);
                acc[rt][0][0] = mfma16(al, w00, acc[rt][0][0]);
                acc[rt][1][0] = mfma16(ah, w01, acc[rt][1][0]);
                acc[rt][1][0] = mfma16(al, w01, acc[rt][1][0]);
                acc[rt][0][1] = mfma16(ah, w10, acc[rt][0][1]);
                acc[rt][0][1] = mfma16(al, w10, acc[rt][0][1]);
                acc[rt][1][1] = mfma16(ah, w11, acc[rt][1][1]);
                acc[rt][1][1] = mfma16(al, w11, acc[rt][1][1]);
            }
        }
        // ===== per-k sequential: store Wxh (scaled) -> phase 2 =====
        #pragma unroll
        for (int kk = 0; kk < 2; ++kk) {
            __syncthreads();   // previous Wxh readers done
            #pragma unroll
            for (int rt = 0; rt < 3; ++rt)
                #pragma unroll
                for (int j2 = 0; j2 < 2; ++j2) {
                    const int cl = (j2 ? (wave + 4) : wave) * 16 + l15;
                    #pragma unroll
                    for (int r = 0; r < 4; ++r) {
                        const int row = rt * 16 + quad * 4 + r;
                        Wxh[row * WXSTR + cl] = (f16)(acc[rt][j2][kk][r]);
                    }
                }
            __syncthreads();
            // phase 2: S_kk += Wxh * (Xh + Xl)^T (9 tiles over 4 waves)
            #pragma unroll
            for (int it = 0; it < 3; ++it) {
                const int p = wave + it * 4;
                if (p < 9) {
                    const int nt = p / 3, mt = p % 3;
                    const f16* wxh_p = Wxh + (nt * 16 + l15) * WXSTR + quad * 8;
                    #pragma unroll
                    for (int kc2 = 0; kc2 < 4; ++kc2) {
                        f16x8 pah = *(const f16x8*)(wxh_p + kc2 * 32);
                        f16x8 pbh = Xh[(mt * 8 + h * 4 + kc2) * 64 + lane];
                        f16x8 pbl = Xlg[(mt * 8 + h * 4 + kc2) * 64 + lane];
                        sacc[kk][it] = mfma16(pah, pbh, sacc[kk][it]);
                        sacc[kk][it] = mfma16(pah, pbl, sacc[kk][it]);
                    }
                }
            }
        }
    }

    // ===== epilogue: T = tanh(S + v1 + v2) -> Ts (chunk-padded, overlays Wxh) =====
    __syncthreads();
    float* Ts = (float*)Wxh;   // padded: addr = idx + (idx>>3); max 2914 f32 <= 3264
    #pragma unroll
    for (int kk = 0; kk < 2; ++kk)
        #pragma unroll
        for (int it = 0; it < 3; ++it) {
            const int p = wave + it * 4;
            if (p < 9) {
                const int nt = p / 3, mt = p % 3;
                const int m = mt * 16 + l15;
                if (m < NF) {
                    #pragma unroll
                    for (int r = 0; r < 4; ++r) {
                        const int n = nt * 16 + quad * 4 + r;
                        if (n < NF) {
                            // x = 2*log2e * (S + v1 + v2); S = sacc * 0.0625
                            float x = sacc[kk][it][r] * C1F
                                      + v1s2[kk * 36 + n] + v2s2[kk * 36 + m];
                            float e = exp2f(x);
                            const int idx = kk * NN2 + n * NF + m;
                            Ts[idx + (idx >> 3)] = 1.f - 2.f / (e + 1.f);
                        }
                    }
                }
            }
        }
    __syncthreads();
    // U-dot: logit u consumes T_flat[u*8 .. u*8+7] = Ts[9u .. 9u+7]
    #pragma unroll
    for (int u0 = 0; u0 < 2; ++u0) {
        const int u = t + u0 * 256;
        if (u < 324) {
            const float* tp = Ts + u * 9;
            float lg = Uws[8];
            #pragma unroll
            for (int j = 0; j < 8; ++j) lg += Uws[j] * tp[j];
            Ls[u] = lg;
        }
    }
    __syncthreads();
    // fused softmax: this block's 324 logits = rows [kp*9, kp*9+9) of out[b]
    #pragma unroll
    for (int rr0 = 0; rr0 < 3; ++rr0) {
        const int rr = wave + rr0 * 4;
        if (rr < 9) {
            float v = (lane < NF) ? Ls[rr * 36 + lane] : -INFINITY;
            float mx = v;
            #pragma unroll
            for (int off = 32; off > 0; off >>= 1) mx = fmaxf(mx, __shfl_xor(mx, off));
            float e = (lane < NF) ? __expf(v - mx) : 0.f;
            float sm = e;
            #pragma unroll
            for (int off = 32; off > 0; off >>= 1) sm += __shfl_xor(sm, off);
            if (lane < NF)
                out[(size_t)b * NN2 + kp * 324 + rr * 36 + lane] = e / sm;
        }
    }
}

extern "C" void kernel_launch(void* const* d_in, const int* in_sizes, int n_in,
                              void* d_out, int out_size, void* d_ws, size_t ws_size,
                              hipStream_t stream) {
    const float* texts = (const float*)d_in[0];
    const float* W     = (const float*)d_in[1];
    const float* Wb    = (const float*)d_in[2];
    const float* V1w   = (const float*)d_in[3];
    const float* V1b   = (const float*)d_in[4];
    const float* V2w   = (const float*)d_in[5];
    const float* V2b   = (const float*)d_in[6];
    const float* Uw    = (const float*)d_in[7];
    const float* Ub    = (const float*)d_in[8];

    char* ws = (char*)d_ws;
    f16x8* WfH = (f16x8*)ws;                                   //  1 MiB
    f16x8* XfH = (f16x8*)(ws + (1 << 20));                     // 24 MiB
    f16x8* XfL = (f16x8*)(ws + (1 << 20) + (size_t)NB * NFRAG * 16);       // 24 MiB
    float* v12 = (float*)(ws + (1 << 20) + (size_t)2 * NB * NFRAG * 16);   // 2.25 MiB
    float* outp = (float*)d_out;

    hipFuncSetAttribute((const void*)prep_all,
                        hipFuncAttributeMaxDynamicSharedMemorySize, SMEM_PREP);
    hipFuncSetAttribute((const void*)ntn_main,
                        hipFuncAttributeMaxDynamicSharedMemorySize, SMEM_MAIN);

    prep_all<<<128 + NB, 256, SMEM_PREP, stream>>>(W, WfH, texts, XfH, XfL,
                                                   V1w, V1b, V2w, V2b, Wb, v12);
    ntn_main<<<NB * NK / 2, 256, SMEM_MAIN, stream>>>(XfH, XfL, WfH, v12, Uw, Ub, outp);
}

// Round 6
// 203.515 us; speedup vs baseline: 2.7294x; 1.1514x over previous
//
#include <hip/hip_runtime.h>
#include <math.h>

#define NB 1024
#define NF 36
#define ED 256
#define NK 8
#define NN2 1296   // 36*36
#define QPK 162    // 1296/8

typedef _Float16 f16;
typedef f16 f16x8 __attribute__((ext_vector_type(8)));
typedef float f32x4 __attribute__((ext_vector_type(4)));

#define WXSTR 136     // f16 per Wx half-row (128 + 8 pad); 272B = 17*16 (b128-aligned)
#define WXHSZ 13056   // 48 * WXSTR * 2 bytes
#define NFRAG 1536    // 3 row-tiles * 8 kc * 64 lanes, f16x8 each

// ---- ntn_main LDS: Xh | Wxh/Ts | v1 v2 Uw L  = 39540 B -> 4 blocks/CU ----
#define XH_OFF  0
#define WXH_OFF 24576
#define V_OFF   (24576 + WXHSZ)                  // 37632
#define SMEM_MAIN (V_OFF + (72 + 72 + 9 + 324) * 4)   // 39540; 4x = 158160 <= 163840

// ---- prep_all LDS: VfH | VfL | partials  = 28672 B -> 5 blocks/CU ----
// (W-pack blocks overlay a [16][264] f16 tile = 8448 B in the same region)
#define PVH_OFF 0
#define PVL_OFF 8192
#define PP_OFF  16384
#define SMEM_PREP 28672

#define TWO_LOG2E 2.8853900817779268f
#define C1F (0.0625f * TWO_LOG2E)

__device__ __forceinline__ f32x4 mfma16(f16x8 a, f16x8 b, f32x4 c) {
    return __builtin_amdgcn_mfma_f32_16x16x32_f16(a, b, c, 0, 0, 0);
}

// blocks [0,128): W fragment pack, one (k,ct) tile per block.
// blocks [128,1152): X fragment pack (register-resident) + v12 via per-wave
//   kc-partial MFMAs + LDS reduction.
// Wb is folded into the v2 row: v2'[k,m] = (V2w[k]+Wb[k]).x_m + V2b[k].
__global__ __launch_bounds__(256, 4) void prep_all(
    const float* __restrict__ W, f16x8* __restrict__ WfH,
    const float* __restrict__ texts, f16x8* __restrict__ XfH, f16x8* __restrict__ XfL,
    const float* __restrict__ V1w, const float* __restrict__ V1b,
    const float* __restrict__ V2w, const float* __restrict__ V2b,
    const float* __restrict__ Wb, float* __restrict__ v12)
{
    extern __shared__ char psmem[];
    const int blk = blockIdx.x;
    const int t = threadIdx.x;
    const int wave = t >> 6, lane = t & 63;

    if (blk < 128) {   // ---- W pack: (k, ct) tile ----
        const int k = blk >> 4, ct = blk & 15;
        f16* Wl = (f16*)psmem;                    // [16][264] f16, scaled x16
        {
            const int r = t >> 4, seg = t & 15;   // row in tile, 16-float segment
            const float* src = W + ((size_t)(k * 256 + ct * 16 + r)) * 256 + seg * 16;
            f16* d = Wl + r * 264 + seg * 16;
            #pragma unroll
            for (int j4 = 0; j4 < 4; ++j4) {
                float4 a = ((const float4*)src)[j4];
                d[j4 * 4 + 0] = (f16)(a.x * 16.0f);
                d[j4 * 4 + 1] = (f16)(a.y * 16.0f);
                d[j4 * 4 + 2] = (f16)(a.z * 16.0f);
                d[j4 * 4 + 3] = (f16)(a.w * 16.0f);
            }
        }
        __syncthreads();
        f16x8* dst = WfH + (size_t)(k * 16 + ct) * 8 * 64;
        #pragma unroll
        for (int e0 = 0; e0 < 2; ++e0) {
            const int e = t + e0 * 256;           // [0,512) output entries
            const int kc = e >> 6, el = e & 63, qd = el >> 4, l15 = el & 15;
            dst[e] = *(const f16x8*)(Wl + l15 * 264 + (kc * 4 + qd) * 8);
        }
        return;
    }

    // ---- X fragment pack + v12 ----
    f16x8* VfH = (f16x8*)(psmem + PVH_OFF);
    f16x8* VfL = (f16x8*)(psmem + PVL_OFF);
    f32x4* Pp  = (f32x4*)(psmem + PP_OFF);        // [4 waves][3 rt][64 lanes]

    const int b = blk - 128;
    const float* xb = texts + (size_t)b * NF * ED;

    // V fragments: col = which*8 + k at lane&15; scaled by 16; Wb folded into V2
    #pragma unroll
    for (int i0 = 0; i0 < 2; ++i0) {
        int i = t + i0 * 256;          // [0,512)
        int kc = (i >> 6) & 7, ln = i & 63;
        int q = ln >> 4, col = ln & 15;
        int which = col >> 3, kk = col & 7;
        const float* src  = (which ? V2w : V1w) + kk * 256 + kc * 32 + q * 8;
        const float* srcb = Wb + kk * 256 + kc * 32 + q * 8;
        f16x8 hi, lo;
        #pragma unroll
        for (int j = 0; j < 8; ++j) {
            float sv = src[j] + (which ? srcb[j] : 0.f);
            sv *= 16.0f;
            f16 h = (f16)sv;
            hi[j] = h;
            lo[j] = (f16)(sv - (float)h);
        }
        VfH[i] = hi;
        VfL[i] = lo;
    }

    // X fragments: direct global gather -> registers + global store.
    f16x8 FH[6], FL[6];
    #pragma unroll
    for (int i0 = 0; i0 < 6; ++i0) {
        int i = t + i0 * 256;          // [0,1536)
        int rt = i >> 9, kc = (i >> 6) & 7;
        int q = lane >> 4, l15 = lane & 15;
        int row = rt * 16 + l15;
        f16x8 hi, lo;
        if (row < NF) {
            const float* s = xb + row * ED + kc * 32 + q * 8;
            float4 a = *(const float4*)s;
            float4 c = *(const float4*)(s + 4);
            float v[8] = {a.x, a.y, a.z, a.w, c.x, c.y, c.z, c.w};
            #pragma unroll
            for (int j = 0; j < 8; ++j) {
                f16 h = (f16)v[j];
                hi[j] = h;
                lo[j] = (f16)(v[j] - (float)h);
            }
        } else {
            #pragma unroll
            for (int j = 0; j < 8; ++j) { hi[j] = (f16)0.f; lo[j] = (f16)0.f; }
        }
        FH[i0] = hi;
        FL[i0] = lo;
        XfH[(size_t)b * NFRAG + i] = hi;
        XfL[(size_t)b * NFRAG + i] = lo;
    }
    __syncthreads();   // VfH/VfL staged

    // per-wave kc-partials of v12 (kc = wave and wave+4), all 3 row-tiles
    f32x4 pacc[3];
    #pragma unroll
    for (int rt = 0; rt < 3; ++rt) pacc[rt] = (f32x4){0.f, 0.f, 0.f, 0.f};
    #pragma unroll
    for (int rt = 0; rt < 3; ++rt) {
        #pragma unroll
        for (int s = 0; s < 2; ++s) {
            const int i0 = rt * 2 + s;          // frag (rt, kc = wave + 4*s)
            const int kc = wave + 4 * s;
            f16x8 bh = VfH[kc * 64 + lane];
            f16x8 bl = VfL[kc * 64 + lane];
            pacc[rt] = mfma16(FH[i0], bh, pacc[rt]);
            pacc[rt] = mfma16(FH[i0], bl, pacc[rt]);
            pacc[rt] = mfma16(FL[i0], bh, pacc[rt]);
        }
    }
    #pragma unroll
    for (int rt = 0; rt < 3; ++rt)
        Pp[(wave * 3 + rt) * 64 + lane] = pacc[rt];
    __syncthreads();

    // reduce 4 wave-partials; wave rt (<3) owns row-tile rt
    if (wave < 3) {
        f32x4 acc = Pp[(0 * 3 + wave) * 64 + lane];
        #pragma unroll
        for (int w = 1; w < 4; ++w) acc += Pp[(w * 3 + wave) * 64 + lane];
        const int q = lane >> 4, l15 = lane & 15;
        const int which = l15 >> 3, kk = l15 & 7;
        const float bias = which ? V2b[kk] : V1b[kk];
        #pragma unroll
        for (int r = 0; r < 4; ++r) {
            const int n = wave * 16 + q * 4 + r;
            if (n < NF)
                v12[((size_t)b * 16 + l15) * NF + n] = acc[r] * 0.0625f + bias;
        }
    }
}

// k-pair merged main (Xh staged in LDS, X-lo from global) + fused softmax.
// Phase 1 numerics: Wx = Xh * Wh ONLY. The dropped Xl*Wh term is a ~2^-11
// relative correction, below the f16 quantization floor of the Wxh store
// (same principle as the validated "no Wx-lo"). Phase 2 keeps Xh+Xl, where
// X-lo acts on S directly (un-masked).
// Wxh stays *16-scaled (exact in f16); 0.0625*2*log2e folded into epilogue fma.
__global__ __launch_bounds__(256, 4) void ntn_main(
    const f16x8* __restrict__ XfHG, const f16x8* __restrict__ XfLG,
    const f16x8* __restrict__ WfH,
    const float* __restrict__ v12,
    const float* __restrict__ Uw, const float* __restrict__ Ubp,
    float* __restrict__ out)
{
    extern __shared__ char smem[];
    f16x8* Xh   = (f16x8*)(smem + XH_OFF);
    f16*   Wxh  = (f16*)(smem + WXH_OFF);
    float* v1s2 = (float*)(smem + V_OFF);      // [2][36], pre-scaled by 2*log2e
    float* v2s2 = v1s2 + 72;                   // [2][36]
    float* Uws  = v1s2 + 144;                  // [9]
    float* Ls   = v1s2 + 153;                  // [324] logits

    // XCD swizzle: the 4 k-pair blocks of a given b share id&7 (same XCD)
    const int id  = blockIdx.x;
    const int xcd = id & 7;
    const int rem = id >> 3;
    const int kp  = rem & 3;
    const int b   = ((rem >> 2) << 3) | xcd;
    const int k0  = kp * 2;

    const int t    = threadIdx.x;
    const int wave = t >> 6;
    const int lane = t & 63;
    const int quad = lane >> 4;
    const int l15  = lane & 15;

    const f16x8* Xlg = XfLG + (size_t)b * NFRAG;   // X-lo: global (L2/L1)

    // ---- stage X-hi fragments into LDS (coalesced dwordx4) ----
    {
        const f16x8* gh = XfHG + (size_t)b * NFRAG;
        #pragma unroll
        for (int i = 0; i < 6; ++i) Xh[t + i * 256] = gh[t + i * 256];
    }
    if (t < 144) {
        const int r = t / 36, n = t - r * 36;
        const int which = r & 1, kq = r >> 1;
        float v = v12[((size_t)b * 16 + which * 8 + (k0 + kq)) * NF + n] * TWO_LOG2E;
        (which ? v2s2 : v1s2)[kq * 36 + n] = v;
    }
    if (t < 8) Uws[t] = Uw[t];
    if (t == 8) Uws[8] = Ubp[0];
    __syncthreads();

    const f16x8* Wk0 = WfH + (size_t)k0 * 8192;   // 16ct*8kc*64
    const f16x8* Wk1 = Wk0 + 8192;

    f32x4 sacc[2][3];
    #pragma unroll
    for (int kk = 0; kk < 2; ++kk)
        #pragma unroll
        for (int it = 0; it < 3; ++it) sacc[kk][it] = (f32x4){0.f, 0.f, 0.f, 0.f};

    for (int h = 0; h < 2; ++h) {
        // ===== phase 1: Wx[:, half h] for BOTH k's; Xh-only (see header) =====
        f32x4 acc[3][2][2];   // [rt][ctslot][kk]
        #pragma unroll
        for (int i = 0; i < 3; ++i)
            #pragma unroll
            for (int j = 0; j < 2; ++j) {
                acc[i][j][0] = (f32x4){0.f, 0.f, 0.f, 0.f};
                acc[i][j][1] = (f32x4){0.f, 0.f, 0.f, 0.f};
            }
        const int ct0 = h * 8 + wave;
        const int ct1 = ct0 + 4;
        #pragma unroll 2
        for (int kc = 0; kc < 8; ++kc) {
            f16x8 w00 = Wk0[(ct0 * 8 + kc) * 64 + lane];
            f16x8 w01 = Wk0[(ct1 * 8 + kc) * 64 + lane];
            f16x8 w10 = Wk1[(ct0 * 8 + kc) * 64 + lane];
            f16x8 w11 = Wk1[(ct1 * 8 + kc) * 64 + lane];
            #pragma unroll
            for (int rt = 0; rt < 3; ++rt) {
                f16x8 ah = Xh[(rt * 8 + kc) * 64 + lane];    // LDS ds_read_b128
                acc[rt][0][0] = mfma16(ah, w00, acc[rt][0][0]);
                acc[rt][1][0] = mfma16(ah, w01, acc[rt][1][0]);
                acc[rt][0][1] = mfma16(ah, w10, acc[rt][0][1]);
                acc[rt][1][1] = mfma16(ah, w11, acc[rt][1][1]);
            }
        }
        // ===== per-k sequential: store Wxh (scaled) -> phase 2 =====
        #pragma unroll
        for (int kk = 0; kk < 2; ++kk) {
            __syncthreads();   // previous Wxh readers done
            #pragma unroll
            for (int rt = 0; rt < 3; ++rt)
                #pragma unroll
                for (int j2 = 0; j2 < 2; ++j2) {
                    const int cl = (j2 ? (wave + 4) : wave) * 16 + l15;
                    #pragma unroll
                    for (int r = 0; r < 4; ++r) {
                        const int row = rt * 16 + quad * 4 + r;
                        Wxh[row * WXSTR + cl] = (f16)(acc[rt][j2][kk][r]);
                    }
                }
            __syncthreads();
            // phase 2: S_kk += Wxh * (Xh + Xl)^T (9 tiles over 4 waves)
            #pragma unroll
            for (int it = 0; it < 3; ++it) {
                const int p = wave + it * 4;
                if (p < 9) {
                    const int nt = p / 3, mt = p % 3;
                    const f16* wxh_p = Wxh + (nt * 16 + l15) * WXSTR + quad * 8;
                    #pragma unroll
                    for (int kc2 = 0; kc2 < 4; ++kc2) {
                        f16x8 pah = *(const f16x8*)(wxh_p + kc2 * 32);
                        f16x8 pbh = Xh[(mt * 8 + h * 4 + kc2) * 64 + lane];
                        f16x8 pbl = Xlg[(mt * 8 + h * 4 + kc2) * 64 + lane];
                        sacc[kk][it] = mfma16(pah, pbh, sacc[kk][it]);
                        sacc[kk][it] = mfma16(pah, pbl, sacc[kk][it]);
                    }
                }
            }
        }
    }

    // ===== epilogue: T = tanh(S + v1 + v2) -> Ts (chunk-padded, overlays Wxh) =====
    __syncthreads();
    float* Ts = (float*)Wxh;   // padded: addr = idx + (idx>>3)
    #pragma unroll
    for (int kk = 0; kk < 2; ++kk)
        #pragma unroll
        for (int it = 0; it < 3; ++it) {
            const int p = wave + it * 4;
            if (p < 9) {
                const int nt = p / 3, mt = p % 3;
                const int m = mt * 16 + l15;
                if (m < NF) {
                    #pragma unroll
                    for (int r = 0; r < 4; ++r) {
                        const int n = nt * 16 + quad * 4 + r;
                        if (n < NF) {
                            // x = 2*log2e * (S + v1 + v2); S = sacc * 0.0625
                            float x = sacc[kk][it][r] * C1F
                                      + v1s2[kk * 36 + n] + v2s2[kk * 36 + m];
                            float e = exp2f(x);
                            const int idx = kk * NN2 + n * NF + m;
                            Ts[idx + (idx >> 3)] = 1.f - 2.f / (e + 1.f);
                        }
                    }
                }
            }
        }
    __syncthreads();
    // U-dot: logit u consumes T_flat[u*8 .. u*8+7] = Ts[9u .. 9u+7]
    #pragma unroll
    for (int u0 = 0; u0 < 2; ++u0) {
        const int u = t + u0 * 256;
        if (u < 324) {
            const float* tp = Ts + u * 9;
            float lg = Uws[8];
            #pragma unroll
            for (int j = 0; j < 8; ++j) lg += Uws[j] * tp[j];
            Ls[u] = lg;
        }
    }
    __syncthreads();
    // fused softmax: this block's 324 logits = rows [kp*9, kp*9+9) of out[b]
    #pragma unroll
    for (int rr0 = 0; rr0 < 3; ++rr0) {
        const int rr = wave + rr0 * 4;
        if (rr < 9) {
            float v = (lane < NF) ? Ls[rr * 36 + lane] : -INFINITY;
            float mx = v;
            #pragma unroll
            for (int off = 32; off > 0; off >>= 1) mx = fmaxf(mx, __shfl_xor(mx, off));
            float e = (lane < NF) ? __expf(v - mx) : 0.f;
            float sm = e;
            #pragma unroll
            for (int off = 32; off > 0; off >>= 1) sm += __shfl_xor(sm, off);
            if (lane < NF)
                out[(size_t)b * NN2 + kp * 324 + rr * 36 + lane] = e / sm;
        }
    }
}

extern "C" void kernel_launch(void* const* d_in, const int* in_sizes, int n_in,
                              void* d_out, int out_size, void* d_ws, size_t ws_size,
                              hipStream_t stream) {
    const float* texts = (const float*)d_in[0];
    const float* W     = (const float*)d_in[1];
    const float* Wb    = (const float*)d_in[2];
    const float* V1w   = (const float*)d_in[3];
    const float* V1b   = (const float*)d_in[4];
    const float* V2w   = (const float*)d_in[5];
    const float* V2b   = (const float*)d_in[6];
    const float* Uw    = (const float*)d_in[7];
    const float* Ub    = (const float*)d_in[8];

    char* ws = (char*)d_ws;
    f16x8* WfH = (f16x8*)ws;                                   //  1 MiB
    f16x8* XfH = (f16x8*)(ws + (1 << 20));                     // 24 MiB
    f16x8* XfL = (f16x8*)(ws + (1 << 20) + (size_t)NB * NFRAG * 16);       // 24 MiB
    float* v12 = (float*)(ws + (1 << 20) + (size_t)2 * NB * NFRAG * 16);   // 2.25 MiB
    float* outp = (float*)d_out;

    hipFuncSetAttribute((const void*)prep_all,
                        hipFuncAttributeMaxDynamicSharedMemorySize, SMEM_PREP);
    hipFuncSetAttribute((const void*)ntn_main,
                        hipFuncAttributeMaxDynamicSharedMemorySize, SMEM_MAIN);

    prep_all<<<128 + NB, 256, SMEM_PREP, stream>>>(W, WfH, texts, XfH, XfL,
                                                   V1w, V1b, V2w, V2b, Wb, v12);
    ntn_main<<<NB * NK / 2, 256, SMEM_MAIN, stream>>>(XfH, XfL, WfH, v12, Uw, Ub, outp);
}